// Round 2
// baseline (200.540 us; speedup 1.0000x reference)
//
#include <hip/hip_runtime.h>

// YOLOv2 loss, fused single-pass, branchless, float2-vectorized.
// Input layout: x[n, c, h, w], c = a*85 + k, strides: n=425*2704, c=2704, hw=1.
// One thread per PAIR of adjacent cells (n, hw, hw+1) -> float2 loads (512 B/inst/wave).
// All masks applied as 0/1 multiplies: zero exec-mask divergence, straight-line
// score loop that the compiler can unroll with many loads outstanding.

#define A_N 5
#define KPA 85
#define N_BATCH 64
#define HW 2704               // 52*52
#define HW2 (HW / 2)          // 1352 float2-pairs per image
#define CSTRIDE 2704
#define NSTRIDE (425 * 2704)
#define N_PAIRS (N_BATCH * HW2)   // 86528 = 676 * 128 exactly
#define WPOS 5.0f
#define WNOOBJ 0.5f
#define EPSF 1e-8f

__device__ __forceinline__ float2 ld2(const float* __restrict__ p, int elem_off) {
    return *reinterpret_cast<const float2*>(p + elem_off);
}

__global__ __launch_bounds__(128) void yolo_loss_kernel(
    const float* __restrict__ out, const float* __restrict__ gt,
    float* __restrict__ loss)
{
    const int idx = blockIdx.x * blockDim.x + threadIdx.x;  // < N_PAIRS exactly
    const int n  = idx / HW2;
    const int p  = idx - n * HW2;
    const int base = n * NSTRIDE + p * 2;   // max ~73.5M, fits int; 8B-aligned

    float acc0 = 0.0f, acc1 = 0.0f;        // per-cell accumulators (x, y)

    // ---- gt confidences + out confidences for all 5 anchors ----
    float gc0[A_N], gc1[A_N], oc0[A_N], oc1[A_N];
#pragma unroll
    for (int a = 0; a < A_N; ++a) {
        float2 g = ld2(gt,  base + (a * KPA + 4) * CSTRIDE);
        float2 o = ld2(out, base + (a * KPA + 4) * CSTRIDE);
        gc0[a] = g.x; gc1[a] = g.y; oc0[a] = o.x; oc1[a] = o.y;
        // no-object confidence loss: mask = (g_conf == 0)
        acc0 += (g.x == 0.0f ? WNOOBJ : 0.0f) * o.x * o.x;
        acc1 += (g.y == 0.0f ? WNOOBJ : 0.0f) * o.y * o.y;
    }

    // ---- gt box = anchor 0's position ----
    float gb0[4], gb1[4];
#pragma unroll
    for (int k = 0; k < 4; ++k) {
        float2 g = ld2(gt, base + k * CSTRIDE);
        gb0[k] = g.x; gb1[k] = g.y;
    }
    const float areaB0 = fmaxf(gb0[2] - gb0[0], 0.0f) * fmaxf(gb0[3] - gb0[1], 0.0f);
    const float areaB1 = fmaxf(gb1[2] - gb1[0], 0.0f) * fmaxf(gb1[3] - gb1[1], 0.0f);

    // ---- predicted boxes, IoU per anchor ----
    float op0[A_N][4], op1[A_N][4], iou0[A_N], iou1[A_N];
#pragma unroll
    for (int a = 0; a < A_N; ++a) {
#pragma unroll
        for (int k = 0; k < 4; ++k) {
            float2 o = ld2(out, base + (a * KPA + k) * CSTRIDE);
            op0[a][k] = o.x; op1[a][k] = o.y;
        }
        {
            float w = fmaxf(fminf(op0[a][2], gb0[2]) - fmaxf(op0[a][0], gb0[0]), 0.0f);
            float h = fmaxf(fminf(op0[a][3], gb0[3]) - fmaxf(op0[a][1], gb0[1]), 0.0f);
            float inter = w * h;
            float areaA = fmaxf(op0[a][2] - op0[a][0], 0.0f) *
                          fmaxf(op0[a][3] - op0[a][1], 0.0f);
            iou0[a] = inter / (areaA + areaB0 - inter + EPSF);
        }
        {
            float w = fmaxf(fminf(op1[a][2], gb1[2]) - fmaxf(op1[a][0], gb1[0]), 0.0f);
            float h = fmaxf(fminf(op1[a][3], gb1[3]) - fmaxf(op1[a][1], gb1[1]), 0.0f);
            float inter = w * h;
            float areaA = fmaxf(op1[a][2] - op1[a][0], 0.0f) *
                          fmaxf(op1[a][3] - op1[a][1], 0.0f);
            iou1[a] = inter / (areaA + areaB1 - inter + EPSF);
        }
    }

    // ---- argmax (first max: strict >) ----
    int best0 = 0, best1 = 0;
    float bi0 = iou0[0], bi1 = iou1[0];
#pragma unroll
    for (int a = 1; a < A_N; ++a) {
        if (iou0[a] > bi0) { bi0 = iou0[a]; best0 = a; }
        if (iou1[a] > bi1) { bi1 = iou1[a]; best1 = a; }
    }

    // ---- responsible-anchor terms, branchless over all anchors ----
#pragma unroll
    for (int a = 0; a < A_N; ++a) {
        float lp0 = 0.0f, lp1 = 0.0f;
#pragma unroll
        for (int k = 0; k < 4; ++k) {
            float2 g = ld2(gt, base + (a * KPA + k) * CSTRIDE);
            float d0 = op0[a][k] - g.x;
            float d1 = op1[a][k] - g.y;
            lp0 = fmaf(d0, d0, lp0);
            lp1 = fmaf(d1, d1, lp1);
        }
        float dc0 = oc0[a] - iou0[a];
        float dc1 = oc1[a] - iou1[a];
        float m0 = (a == best0 && gc0[a] > 0.0f) ? 1.0f : 0.0f;
        float m1 = (a == best1 && gc1[a] > 0.0f) ? 1.0f : 0.0f;
        acc0 += m0 * fmaf(WPOS, lp0, dc0 * dc0);
        acc1 += m1 * fmaf(WPOS, lp1, dc1 * dc1);
    }

    // ---- class-score loss: unmasked inner sum, mask applied once per anchor ----
#pragma unroll
    for (int a = 0; a < A_N; ++a) {
        const int sb = base + (a * KPA + 5) * CSTRIDE;
        float s0 = 0.0f, s1 = 0.0f;
#pragma unroll 10
        for (int k = 0; k < 80; ++k) {
            float2 o = ld2(out, sb + k * CSTRIDE);
            float2 g = ld2(gt,  sb + k * CSTRIDE);
            float d0 = o.x - g.x;
            float d1 = o.y - g.y;
            s0 = fmaf(d0, d0, s0);
            s1 = fmaf(d1, d1, s1);
        }
        acc0 += (gc0[a] > 0.0f ? 1.0f : 0.0f) * s0;
        acc1 += (gc1[a] > 0.0f ? 1.0f : 0.0f) * s1;
    }

    // ---- reduction: wave64 shuffle -> LDS -> one atomic per block ----
    float acc = acc0 + acc1;
#pragma unroll
    for (int off = 32; off > 0; off >>= 1)
        acc += __shfl_down(acc, off);

    __shared__ float wsum[2];
    const int lane = threadIdx.x & 63;
    const int wid  = threadIdx.x >> 6;
    if (lane == 0) wsum[wid] = acc;
    __syncthreads();
    if (threadIdx.x == 0) {
        atomicAdd(loss, (wsum[0] + wsum[1]) * (1.0f / N_BATCH));
    }
}

extern "C" void kernel_launch(void* const* d_in, const int* in_sizes, int n_in,
                              void* d_out, int out_size, void* d_ws, size_t ws_size,
                              hipStream_t stream) {
    const float* out_p = (const float*)d_in[0];
    const float* gt_p  = (const float*)d_in[1];
    float* loss = (float*)d_out;

    // d_out is poisoned once and never re-poisoned between graph replays:
    // zero it ourselves every call (capture-safe async memset).
    hipMemsetAsync(loss, 0, sizeof(float), stream);

    const int threads = 128;
    const int blocks = N_PAIRS / threads;  // 676 exactly, all waves resident
    yolo_loss_kernel<<<blocks, threads, 0, stream>>>(out_p, gt_p, loss);
}

// Round 3
// 127.072 us; speedup vs baseline: 1.5782x; 1.5782x over previous
//
#include <hip/hip_runtime.h>

// YOLOv2 loss, fused, two-role single kernel.
//  - Blocks [0, 676):    control terms (IoU/argmax/pos/conf-obj/noobj), one thread/cell,
//                        scalar coalesced loads (round-0 verified logic).
//  - Blocks [676, 1205): score loss (94% of traffic) as a pure float4 stream:
//                        thread <-> (q = hw/4, channel-pair), loops all 64 images.
// Layout: x[n, c, h, w], c = a*85 + k; strides: n=425*2704, c=2704, hw=1.

#define A_N 5
#define KPA 85
#define N_BATCH 64
#define HW 2704                 // 52*52
#define Q4 (HW / 4)             // 676 float4 groups per channel-row
#define CSTRIDE 2704
#define NSTRIDE (425 * 2704)
#define N_CELLS (N_BATCH * HW)  // 173056 = 676 * 256 exactly
#define CTRL_BLOCKS 676
#define N_SCORE_THREADS (Q4 * 200)       // 135200: 200 channel-PAIRS (5a * 80k / 2)
#define SCORE_BLOCKS 529                 // ceil(135200 / 256)
#define WPOS 5.0f
#define WNOOBJ 0.5f
#define EPSF 1e-8f

__device__ __forceinline__ float4 ld4(const float* __restrict__ p, int elem_off) {
    return *reinterpret_cast<const float4*>(p + elem_off);
}

__global__ __launch_bounds__(256) void yolo_loss_kernel(
    const float* __restrict__ out, const float* __restrict__ gt,
    float* __restrict__ loss)
{
    float acc = 0.0f;

    if (blockIdx.x < CTRL_BLOCKS) {
        // ================= control: one thread per cell =================
        const int idx = blockIdx.x * blockDim.x + threadIdx.x;   // < N_CELLS exactly
        const int n  = idx / HW;
        const int hw = idx - n * HW;
        const int base = n * NSTRIDE + hw;

        float gconf[A_N];
        bool anyObj = false, anyNoObj = false;
#pragma unroll
        for (int a = 0; a < A_N; ++a) {
            gconf[a] = gt[base + (a * KPA + 4) * CSTRIDE];
            anyObj   |= (gconf[a] > 0.0f);
            anyNoObj |= (gconf[a] == 0.0f);
        }

        if (anyNoObj) {
#pragma unroll
            for (int a = 0; a < A_N; ++a) {
                if (gconf[a] == 0.0f) {
                    float oc = out[base + (a * KPA + 4) * CSTRIDE];
                    acc += WNOOBJ * oc * oc;
                }
            }
        }

        if (anyObj) {
            float gb0 = gt[base + 0 * CSTRIDE];
            float gb1 = gt[base + 1 * CSTRIDE];
            float gb2 = gt[base + 2 * CSTRIDE];
            float gb3 = gt[base + 3 * CSTRIDE];
            const float areaB = fmaxf(gb2 - gb0, 0.0f) * fmaxf(gb3 - gb1, 0.0f);

            float op[A_N][4];
            float iou[A_N];
#pragma unroll
            for (int a = 0; a < A_N; ++a) {
#pragma unroll
                for (int k = 0; k < 4; ++k)
                    op[a][k] = out[base + (a * KPA + k) * CSTRIDE];
                float w = fmaxf(fminf(op[a][2], gb2) - fmaxf(op[a][0], gb0), 0.0f);
                float h = fmaxf(fminf(op[a][3], gb3) - fmaxf(op[a][1], gb1), 0.0f);
                float inter = w * h;
                float areaA = fmaxf(op[a][2] - op[a][0], 0.0f) *
                              fmaxf(op[a][3] - op[a][1], 0.0f);
                iou[a] = inter / (areaA + areaB - inter + EPSF);
            }
            float best_iou = -1.0f;   // strict > keeps first max
            int best = 0;
#pragma unroll
            for (int a = 0; a < A_N; ++a) {
                if (iou[a] > best_iou) { best_iou = iou[a]; best = a; }
            }

            if (gconf[best] > 0.0f) {
                float lp = 0.0f;
#pragma unroll
                for (int k = 0; k < 4; ++k) {
                    float g = gt[base + (best * KPA + k) * CSTRIDE];
                    float d = op[best][k] - g;
                    lp = fmaf(d, d, lp);
                }
                acc += WPOS * lp;
                float oc = out[base + (best * KPA + 4) * CSTRIDE];
                float d = oc - best_iou;
                acc += d * d;
            }
        }
    } else {
        // ================= score: float4 streaming =================
        const int stid = (blockIdx.x - CTRL_BLOCKS) * blockDim.x + threadIdx.x;
        if (stid < N_SCORE_THREADS) {
            const int cpair = stid / Q4;             // [0, 200)
            const int q     = stid - cpair * Q4;     // [0, 676)
            const int a     = cpair / 40;            // [0, 5): 40 pairs per anchor
            const int kk    = (cpair - a * 40) * 2;  // [0, 80) even
            const int e0 = (a * KPA + 5 + kk) * CSTRIDE + 4 * q;  // score ch kk
            const int e1 = e0 + CSTRIDE;                          // score ch kk+1
            const int eg = (a * KPA + 4) * CSTRIDE + 4 * q;       // gconf ch

            float accA = 0.0f, accB = 0.0f;
#pragma unroll 2
            for (int n = 0; n < N_BATCH; ++n) {
                const int b = n * NSTRIDE;
                float4 o0 = ld4(out, b + e0);
                float4 g0 = ld4(gt,  b + e0);
                float4 o1 = ld4(out, b + e1);
                float4 g1 = ld4(gt,  b + e1);
                float4 gc = ld4(gt,  b + eg);   // L2-resident (3.5 MB total)

                float d0, d1, s;
                d0 = o0.x - g0.x; d1 = o1.x - g1.x; s = fmaf(d0, d0, d1 * d1);
                accA += (gc.x > 0.0f) ? s : 0.0f;
                d0 = o0.y - g0.y; d1 = o1.y - g1.y; s = fmaf(d0, d0, d1 * d1);
                accB += (gc.y > 0.0f) ? s : 0.0f;
                d0 = o0.z - g0.z; d1 = o1.z - g1.z; s = fmaf(d0, d0, d1 * d1);
                accA += (gc.z > 0.0f) ? s : 0.0f;
                d0 = o0.w - g0.w; d1 = o1.w - g1.w; s = fmaf(d0, d0, d1 * d1);
                accB += (gc.w > 0.0f) ? s : 0.0f;
            }
            acc = accA + accB;
        }
    }

    // ---- reduction: wave64 shuffle -> LDS -> one atomic per block ----
#pragma unroll
    for (int off = 32; off > 0; off >>= 1)
        acc += __shfl_down(acc, off);

    __shared__ float wsum[4];
    const int lane = threadIdx.x & 63;
    const int wid  = threadIdx.x >> 6;
    if (lane == 0) wsum[wid] = acc;
    __syncthreads();
    if (threadIdx.x == 0) {
        float s = (wsum[0] + wsum[1] + wsum[2] + wsum[3]) * (1.0f / N_BATCH);
        atomicAdd(loss, s);
    }
}

extern "C" void kernel_launch(void* const* d_in, const int* in_sizes, int n_in,
                              void* d_out, int out_size, void* d_ws, size_t ws_size,
                              hipStream_t stream) {
    const float* out_p = (const float*)d_in[0];
    const float* gt_p  = (const float*)d_in[1];
    float* loss = (float*)d_out;

    // d_out is poisoned once and never re-poisoned between graph replays:
    // zero it ourselves every call (capture-safe async memset).
    hipMemsetAsync(loss, 0, sizeof(float), stream);

    const int blocks = CTRL_BLOCKS + SCORE_BLOCKS;   // 1205
    yolo_loss_kernel<<<blocks, 256, 0, stream>>>(out_p, gt_p, loss);
}

// Round 4
// 114.597 us; speedup vs baseline: 1.7500x; 1.1089x over previous
//
#include <hip/hip_runtime.h>

// YOLOv2 loss, fused, two-role single kernel.
//  - Blocks [0, 676):      control terms (IoU/argmax/pos/conf-obj/noobj),
//                          one thread/cell, scalar coalesced loads (round-0 verified).
//  - Blocks [676, 4901):   score loss (94% of traffic) as float4 streams:
//                          thread <-> (k-chunk of 16 ch, (n,a), q=hw/4),
//                          gconf mask hoisted once per thread, 2 ld4/iter, unroll 4.
// Layout: x[n, c, h, w], c = a*85 + k; strides: n=425*2704, c=2704, hw=1.

#define A_N 5
#define KPA 85
#define N_BATCH 64
#define HW 2704                 // 52*52
#define Q4 (HW / 4)             // 676 float4 groups per channel
#define CSTRIDE 2704
#define NSTRIDE (425 * 2704)
#define N_CELLS (N_BATCH * HW)  // 173056 = 676 * 256 exactly
#define CTRL_BLOCKS 676
#define NA (N_BATCH * A_N)      // 320 (n,a) score blocks
#define SC_TPC (NA * Q4)        // 216320 threads per k-chunk
#define KCHUNK 16
#define NKC (80 / KCHUNK)       // 5 k-chunks
#define SC_THREADS (SC_TPC * NKC)      // 1,081,600
#define SC_BLOCKS (SC_THREADS / 256)   // 4225 exactly
#define WPOS 5.0f
#define WNOOBJ 0.5f
#define EPSF 1e-8f

__device__ __forceinline__ float4 ld4(const float* __restrict__ p, int elem_off) {
    return *reinterpret_cast<const float4*>(p + elem_off);
}

__global__ __launch_bounds__(256) void yolo_loss_kernel(
    const float* __restrict__ out, const float* __restrict__ gt,
    float* __restrict__ loss)
{
    float acc = 0.0f;

    if (blockIdx.x < CTRL_BLOCKS) {
        // ================= control: one thread per cell =================
        const int idx = blockIdx.x * blockDim.x + threadIdx.x;   // < N_CELLS exactly
        const int n  = idx / HW;
        const int hw = idx - n * HW;
        const int base = n * NSTRIDE + hw;

        float gconf[A_N];
        bool anyObj = false, anyNoObj = false;
#pragma unroll
        for (int a = 0; a < A_N; ++a) {
            gconf[a] = gt[base + (a * KPA + 4) * CSTRIDE];
            anyObj   |= (gconf[a] > 0.0f);
            anyNoObj |= (gconf[a] == 0.0f);
        }

        if (anyNoObj) {
#pragma unroll
            for (int a = 0; a < A_N; ++a) {
                if (gconf[a] == 0.0f) {
                    float oc = out[base + (a * KPA + 4) * CSTRIDE];
                    acc += WNOOBJ * oc * oc;
                }
            }
        }

        if (anyObj) {
            float gb0 = gt[base + 0 * CSTRIDE];
            float gb1 = gt[base + 1 * CSTRIDE];
            float gb2 = gt[base + 2 * CSTRIDE];
            float gb3 = gt[base + 3 * CSTRIDE];
            const float areaB = fmaxf(gb2 - gb0, 0.0f) * fmaxf(gb3 - gb1, 0.0f);

            float op[A_N][4];
            float iou[A_N];
#pragma unroll
            for (int a = 0; a < A_N; ++a) {
#pragma unroll
                for (int k = 0; k < 4; ++k)
                    op[a][k] = out[base + (a * KPA + k) * CSTRIDE];
                float w = fmaxf(fminf(op[a][2], gb2) - fmaxf(op[a][0], gb0), 0.0f);
                float h = fmaxf(fminf(op[a][3], gb3) - fmaxf(op[a][1], gb1), 0.0f);
                float inter = w * h;
                float areaA = fmaxf(op[a][2] - op[a][0], 0.0f) *
                              fmaxf(op[a][3] - op[a][1], 0.0f);
                iou[a] = inter / (areaA + areaB - inter + EPSF);
            }
            float best_iou = -1.0f;   // strict > keeps first max
            int best = 0;
#pragma unroll
            for (int a = 0; a < A_N; ++a) {
                if (iou[a] > best_iou) { best_iou = iou[a]; best = a; }
            }

            if (gconf[best] > 0.0f) {
                float lp = 0.0f;
#pragma unroll
                for (int k = 0; k < 4; ++k) {
                    float g = gt[base + (best * KPA + k) * CSTRIDE];
                    float d = op[best][k] - g;
                    lp = fmaf(d, d, lp);
                }
                acc += WPOS * lp;
                float oc = out[base + (best * KPA + 4) * CSTRIDE];
                float d = oc - best_iou;
                acc += d * d;
            }
        }
    } else {
        // ================= score: float4 streaming, gconf hoisted =================
        const int stid = (blockIdx.x - CTRL_BLOCKS) * blockDim.x + threadIdx.x;
        // stid < SC_THREADS exactly (4225 * 256)
        const int kc  = stid / SC_TPC;          // [0, 5)
        const int rem = stid - kc * SC_TPC;     // [0, 216320)
        const int na  = rem / Q4;               // [0, 320)
        const int q   = rem - na * Q4;          // [0, 676)
        const int n   = na / A_N;
        const int a   = na - n * A_N;

        const int gco = n * NSTRIDE + (a * KPA + 4) * CSTRIDE + 4 * q;
        int off = gco + (1 + kc * KCHUNK) * CSTRIDE;  // first of 16 score channels

        const float4 gc = ld4(gt, gco);         // mask, loaded ONCE (L1/L2-resident)

        float sx = 0.0f, sy = 0.0f, sz = 0.0f, sw = 0.0f;
#pragma unroll 4
        for (int k = 0; k < KCHUNK; ++k) {
            float4 o = ld4(out, off);
            float4 g = ld4(gt,  off);
            off += CSTRIDE;
            float d;
            d = o.x - g.x; sx = fmaf(d, d, sx);
            d = o.y - g.y; sy = fmaf(d, d, sy);
            d = o.z - g.z; sz = fmaf(d, d, sz);
            d = o.w - g.w; sw = fmaf(d, d, sw);
        }
        acc = (gc.x > 0.0f ? sx : 0.0f) + (gc.y > 0.0f ? sy : 0.0f) +
              (gc.z > 0.0f ? sz : 0.0f) + (gc.w > 0.0f ? sw : 0.0f);
    }

    // ---- reduction: wave64 shuffle -> LDS -> one atomic per block ----
#pragma unroll
    for (int off = 32; off > 0; off >>= 1)
        acc += __shfl_down(acc, off);

    __shared__ float wsum[4];
    const int lane = threadIdx.x & 63;
    const int wid  = threadIdx.x >> 6;
    if (lane == 0) wsum[wid] = acc;
    __syncthreads();
    if (threadIdx.x == 0) {
        float s = (wsum[0] + wsum[1] + wsum[2] + wsum[3]) * (1.0f / N_BATCH);
        atomicAdd(loss, s);
    }
}

extern "C" void kernel_launch(void* const* d_in, const int* in_sizes, int n_in,
                              void* d_out, int out_size, void* d_ws, size_t ws_size,
                              hipStream_t stream) {
    const float* out_p = (const float*)d_in[0];
    const float* gt_p  = (const float*)d_in[1];
    float* loss = (float*)d_out;

    // d_out is poisoned once and never re-poisoned between graph replays:
    // zero it ourselves every call (capture-safe async memset).
    hipMemsetAsync(loss, 0, sizeof(float), stream);

    const int blocks = CTRL_BLOCKS + SC_BLOCKS;   // 4901
    yolo_loss_kernel<<<blocks, 256, 0, stream>>>(out_p, gt_p, loss);
}

// Round 5
// 106.203 us; speedup vs baseline: 1.8883x; 1.0790x over previous
//
#include <hip/hip_runtime.h>

// YOLOv2 loss, fused single-pass (round-0 structure) + non-temporal loads.
// Every input byte is consumed exactly once -> nt loads skip L1/L2/L3
// allocation churn on the 578 MB read stream.
// Layout: x[n, c, h, w], c = a*85 + k; strides: n=425*2704, c=2704, hw=1.
// One thread per cell (n,h,w); every fixed-c load is 256B contiguous per wave.

#define A_N 5
#define KPA 85
#define N_BATCH 64
#define HW 2704               // 52*52
#define CSTRIDE 2704
#define NSTRIDE (425 * 2704)
#define N_CELLS (N_BATCH * HW)   // 173056 = 676 * 256 exactly
#define WPOS 5.0f
#define WNOOBJ 0.5f
#define EPSF 1e-8f

__device__ __forceinline__ float ldnt(const float* __restrict__ p) {
    return __builtin_nontemporal_load(p);
}

__global__ __launch_bounds__(256) void yolo_loss_kernel(
    const float* __restrict__ out, const float* __restrict__ gt,
    float* __restrict__ loss)
{
    const int idx = blockIdx.x * blockDim.x + threadIdx.x;   // < N_CELLS exactly
    const int n  = idx / HW;
    const int hw = idx - n * HW;
    const int base = n * NSTRIDE + hw;

    float acc = 0.0f;

    // ---- gt confidences for all 5 anchors ----
    float gconf[A_N];
    bool anyObj = false, anyNoObj = false;
#pragma unroll
    for (int a = 0; a < A_N; ++a) {
        gconf[a] = ldnt(gt + base + (a * KPA + 4) * CSTRIDE);
        anyObj   |= (gconf[a] > 0.0f);
        anyNoObj |= (gconf[a] == 0.0f);
    }

    // ---- no-object confidence loss (g_conf exactly zero) ----
    if (anyNoObj) {
#pragma unroll
        for (int a = 0; a < A_N; ++a) {
            if (gconf[a] == 0.0f) {
                float oc = ldnt(out + base + (a * KPA + 4) * CSTRIDE);
                acc += WNOOBJ * oc * oc;
            }
        }
    }

    if (anyObj) {
        // ---- gt box = anchor 0's position ----
        float gb0 = ldnt(gt + base + 0 * CSTRIDE);
        float gb1 = ldnt(gt + base + 1 * CSTRIDE);
        float gb2 = ldnt(gt + base + 2 * CSTRIDE);
        float gb3 = ldnt(gt + base + 3 * CSTRIDE);
        const float areaB = fmaxf(gb2 - gb0, 0.0f) * fmaxf(gb3 - gb1, 0.0f);

        // ---- IoU of each predicted anchor box vs gt box; argmax (first max) ----
        float op[A_N][4];
        float iou[A_N];
#pragma unroll
        for (int a = 0; a < A_N; ++a) {
#pragma unroll
            for (int k = 0; k < 4; ++k)
                op[a][k] = ldnt(out + base + (a * KPA + k) * CSTRIDE);
            float w = fmaxf(fminf(op[a][2], gb2) - fmaxf(op[a][0], gb0), 0.0f);
            float h = fmaxf(fminf(op[a][3], gb3) - fmaxf(op[a][1], gb1), 0.0f);
            float inter = w * h;
            float areaA = fmaxf(op[a][2] - op[a][0], 0.0f) *
                          fmaxf(op[a][3] - op[a][1], 0.0f);
            iou[a] = inter / (areaA + areaB - inter + EPSF);
        }
        float best_iou = -1.0f;   // iou >= 0 always; strict > keeps first max
        int best = 0;
#pragma unroll
        for (int a = 0; a < A_N; ++a) {
            if (iou[a] > best_iou) { best_iou = iou[a]; best = a; }
        }

        // ---- responsible anchor: onehot(best) * has_obj ----
        if (gconf[best] > 0.0f) {
            float lp = 0.0f;
#pragma unroll
            for (int k = 0; k < 4; ++k) {
                float g = ldnt(gt + base + (best * KPA + k) * CSTRIDE);
                float d = op[best][k] - g;
                lp = fmaf(d, d, lp);
            }
            acc += WPOS * lp;
            float oc = ldnt(out + base + (best * KPA + 4) * CSTRIDE);
            float d = oc - best_iou;
            acc += d * d;
        }

        // ---- class-score loss for every anchor with an object ----
#pragma unroll
        for (int a = 0; a < A_N; ++a) {
            if (gconf[a] > 0.0f) {
                const int sb = base + (a * KPA + 5) * CSTRIDE;
                float s = 0.0f;
#pragma unroll 8
                for (int k = 0; k < 80; ++k) {
                    float d = ldnt(out + sb + k * CSTRIDE) -
                              ldnt(gt  + sb + k * CSTRIDE);
                    s = fmaf(d, d, s);
                }
                acc += s;
            }
        }
    }

    // ---- reduction: wave64 shuffle -> LDS -> one atomic per block ----
#pragma unroll
    for (int off = 32; off > 0; off >>= 1)
        acc += __shfl_down(acc, off);

    __shared__ float wsum[4];
    const int lane = threadIdx.x & 63;
    const int wid  = threadIdx.x >> 6;
    if (lane == 0) wsum[wid] = acc;
    __syncthreads();
    if (threadIdx.x == 0) {
        float s = (wsum[0] + wsum[1] + wsum[2] + wsum[3]) * (1.0f / N_BATCH);
        atomicAdd(loss, s);
    }
}

extern "C" void kernel_launch(void* const* d_in, const int* in_sizes, int n_in,
                              void* d_out, int out_size, void* d_ws, size_t ws_size,
                              hipStream_t stream) {
    const float* out_p = (const float*)d_in[0];
    const float* gt_p  = (const float*)d_in[1];
    float* loss = (float*)d_out;

    // d_out is poisoned once and never re-poisoned between graph replays:
    // zero it ourselves every call (capture-safe async memset).
    hipMemsetAsync(loss, 0, sizeof(float), stream);

    const int threads = 256;
    const int blocks = N_CELLS / threads;   // 676 exactly
    yolo_loss_kernel<<<blocks, threads, 0, stream>>>(out_p, gt_p, loss);
}